// Round 2
// baseline (124.017 us; speedup 1.0000x reference)
//
#include <hip/hip_runtime.h>
#include <hip/hip_bf16.h>

// MeanAggregator: out[n, :] = mean_{s<12} feature[idx[n,s], :]
// feature: [200000, 64] f32, idx: [100000, 12] int32, out: [100000, 64] f32
//
// 16 lanes per node, each lane owns one float4 (16B) of the 256B row.
// R2 change: nontemporal store for the output. The 25.6MB streaming output
// write-allocates ~3.2MB per XCD-L2 (80% of the 4MB L2), evicting feature
// rows that have ~6x average reuse. NT store keeps L2 for the gather.

#define N_NODES  100000
#define N_SAMPLE 12
#define D_FEAT   64
#define LANES_PER_NODE 16   // D_FEAT/4 floats per float4

typedef float  fvec4 __attribute__((ext_vector_type(4)));
typedef int    ivec4 __attribute__((ext_vector_type(4)));

__global__ __launch_bounds__(256) void mean_agg_kernel(
    const fvec4* __restrict__ feat4,   // [N_TOTAL, 16] as fvec4
    const int*   __restrict__ idx,     // [N_NODES, N_SAMPLE]
    fvec4*       __restrict__ out4)    // [N_NODES, 16] as fvec4
{
    const int t    = blockIdx.x * blockDim.x + threadIdx.x;
    const int node = t >> 4;          // /16
    const int c    = t & 15;          // float4 slot within the row
    if (node >= N_NODES) return;

    // 12 indices = 3 x int4, contiguous, broadcast across the 16 lanes of
    // this node (L1 absorbs the redundancy).
    const ivec4* nidx = (const ivec4*)(idx + node * N_SAMPLE);
    const ivec4 j0 = nidx[0];
    const ivec4 j1 = nidx[1];
    const ivec4 j2 = nidx[2];

    fvec4 acc = (fvec4)(0.0f);
    // 12 independent gathers in flight.
    acc += feat4[(size_t)j0.x * LANES_PER_NODE + c];
    acc += feat4[(size_t)j0.y * LANES_PER_NODE + c];
    acc += feat4[(size_t)j0.z * LANES_PER_NODE + c];
    acc += feat4[(size_t)j0.w * LANES_PER_NODE + c];
    acc += feat4[(size_t)j1.x * LANES_PER_NODE + c];
    acc += feat4[(size_t)j1.y * LANES_PER_NODE + c];
    acc += feat4[(size_t)j1.z * LANES_PER_NODE + c];
    acc += feat4[(size_t)j1.w * LANES_PER_NODE + c];
    acc += feat4[(size_t)j2.x * LANES_PER_NODE + c];
    acc += feat4[(size_t)j2.y * LANES_PER_NODE + c];
    acc += feat4[(size_t)j2.z * LANES_PER_NODE + c];
    acc += feat4[(size_t)j2.w * LANES_PER_NODE + c];

    acc *= (1.0f / (float)N_SAMPLE);

    // Streaming write-once output: bypass/deprioritize cache allocation.
    __builtin_nontemporal_store(acc, out4 + t);
}

extern "C" void kernel_launch(void* const* d_in, const int* in_sizes, int n_in,
                              void* d_out, int out_size, void* d_ws, size_t ws_size,
                              hipStream_t stream) {
    const fvec4* feat4 = (const fvec4*)d_in[0];
    const int*   idx   = (const int*)d_in[1];
    fvec4*       out4  = (fvec4*)d_out;

    const int total_threads = N_NODES * LANES_PER_NODE;   // 1.6M
    const int block = 256;
    const int grid  = (total_threads + block - 1) / block; // 6250

    mean_agg_kernel<<<grid, block, 0, stream>>>(feat4, idx, out4);
}

// Round 3
// 122.147 us; speedup vs baseline: 1.0153x; 1.0153x over previous
//
#include <hip/hip_runtime.h>
#include <hip/hip_bf16.h>

// MeanAggregator: out[n, :] = mean_{s<12} feature[idx[n,s], :]
// feature: [200000, 64] f32, idx: [100000, 12] int32, out: [100000, 64] f32
//
// 16 lanes per node-slot, each lane owns one float4 (16B) of the 256B row.
// R3 change: 2 nodes per thread -> 24 independent gather loads in flight
// (vs 12). Theory: we are L2-miss *latency* bound (L3-resident working set,
// only 3.5 TB/s achieved, VALUBusy 7%), so doubling per-wave MLP should
// raise achieved bandwidth. FETCH_SIZE predicted unchanged (~141 MB).

#define N_NODES  100000
#define N_HALF   50000
#define N_SAMPLE 12
#define D_FEAT   64
#define LANES_PER_NODE 16   // D_FEAT/4 floats per float4

typedef float  fvec4 __attribute__((ext_vector_type(4)));
typedef int    ivec4 __attribute__((ext_vector_type(4)));

__global__ __launch_bounds__(256) void mean_agg_kernel(
    const fvec4* __restrict__ feat4,   // [N_TOTAL, 16] as fvec4
    const int*   __restrict__ idx,     // [N_NODES, N_SAMPLE]
    fvec4*       __restrict__ out4)    // [N_NODES, 16] as fvec4
{
    const int t     = blockIdx.x * blockDim.x + threadIdx.x;
    const int node0 = t >> 4;          // /16
    const int c     = t & 15;          // float4 slot within the row
    if (node0 >= N_HALF) return;
    const int node1 = node0 + N_HALF;

    // 12 indices per node = 3 x int4, broadcast across the 16 lanes.
    const ivec4* nidx0 = (const ivec4*)(idx + node0 * N_SAMPLE);
    const ivec4* nidx1 = (const ivec4*)(idx + node1 * N_SAMPLE);
    const ivec4 a0 = nidx0[0], a1 = nidx0[1], a2 = nidx0[2];
    const ivec4 b0 = nidx1[0], b1 = nidx1[1], b2 = nidx1[2];

    fvec4 acc0 = (fvec4)(0.0f);
    fvec4 acc1 = (fvec4)(0.0f);

    // 24 independent gathers in flight.
    acc0 += feat4[(size_t)a0.x * LANES_PER_NODE + c];
    acc0 += feat4[(size_t)a0.y * LANES_PER_NODE + c];
    acc0 += feat4[(size_t)a0.z * LANES_PER_NODE + c];
    acc0 += feat4[(size_t)a0.w * LANES_PER_NODE + c];
    acc0 += feat4[(size_t)a1.x * LANES_PER_NODE + c];
    acc0 += feat4[(size_t)a1.y * LANES_PER_NODE + c];
    acc0 += feat4[(size_t)a1.z * LANES_PER_NODE + c];
    acc0 += feat4[(size_t)a1.w * LANES_PER_NODE + c];
    acc0 += feat4[(size_t)a2.x * LANES_PER_NODE + c];
    acc0 += feat4[(size_t)a2.y * LANES_PER_NODE + c];
    acc0 += feat4[(size_t)a2.z * LANES_PER_NODE + c];
    acc0 += feat4[(size_t)a2.w * LANES_PER_NODE + c];

    acc1 += feat4[(size_t)b0.x * LANES_PER_NODE + c];
    acc1 += feat4[(size_t)b0.y * LANES_PER_NODE + c];
    acc1 += feat4[(size_t)b0.z * LANES_PER_NODE + c];
    acc1 += feat4[(size_t)b0.w * LANES_PER_NODE + c];
    acc1 += feat4[(size_t)b1.x * LANES_PER_NODE + c];
    acc1 += feat4[(size_t)b1.y * LANES_PER_NODE + c];
    acc1 += feat4[(size_t)b1.z * LANES_PER_NODE + c];
    acc1 += feat4[(size_t)b1.w * LANES_PER_NODE + c];
    acc1 += feat4[(size_t)b2.x * LANES_PER_NODE + c];
    acc1 += feat4[(size_t)b2.y * LANES_PER_NODE + c];
    acc1 += feat4[(size_t)b2.z * LANES_PER_NODE + c];
    acc1 += feat4[(size_t)b2.w * LANES_PER_NODE + c];

    const float inv = 1.0f / (float)N_SAMPLE;
    acc0 *= inv;
    acc1 *= inv;

    __builtin_nontemporal_store(acc0, out4 + (size_t)node0 * LANES_PER_NODE + c);
    __builtin_nontemporal_store(acc1, out4 + (size_t)node1 * LANES_PER_NODE + c);
}

extern "C" void kernel_launch(void* const* d_in, const int* in_sizes, int n_in,
                              void* d_out, int out_size, void* d_ws, size_t ws_size,
                              hipStream_t stream) {
    const fvec4* feat4 = (const fvec4*)d_in[0];
    const int*   idx   = (const int*)d_in[1];
    fvec4*       out4  = (fvec4*)d_out;

    const int total_threads = N_HALF * LANES_PER_NODE;     // 800K
    const int block = 256;
    const int grid  = (total_threads + block - 1) / block; // 3125

    mean_agg_kernel<<<grid, block, 0, stream>>>(feat4, idx, out4);
}